// Round 8
// baseline (299.635 us; speedup 1.0000x reference)
//
#include <hip/hip_runtime.h>
#include <math.h>

// B=64, Q=4096, N=256, 20 fg classes + 1 bg. Output (B,Q,N) fp32 = 268 MB.
// P(pair active) ~ 0.027%; P(q-row of 256 has any active) ~ 6.6%.
//
// Ledger: R0 fused+staged = 294.9 (matcher ~114us; storeless ~91us per R1).
// R2-R4 launch_bounds(256,6) = 314.8 (spills). R5 4-row ILP = 297.5 (null).
// R6 voxel mask (-84% d2 work) = 310.9 (negative). R7 LDS shave = 295.7
// (null -- BUT grid was 1024 blocks = exactly 4/CU, so waves never rose).
// Per-wave BW: matcher 0.64 GB/s/wave @16 waves/CU vs fill 0.72 @32 ->
// aggregate tracks wave count; waves are ~95% stalled. R8 doubles waves
// for real: TQ=64 -> 4096 blocks; slow-path state recomputed from global
// (fast path ~40 VGPR, launch_bounds(256,8) -> 64-VGPR cap without spill
// pressure); LDS 8.2 KB -> 8 blocks/CU (wave-slot-capped) = 32 waves/CU.
#define BQ 64
#define QQ 4096
#define NN 256
#define NC 20
#define NL 21
#define TQ 64           // queries per block (grid 64x64 = 4096 blocks)
#define GEO_STRIDE 12   // 10 floats used + 2 pad -> 48 B, ds_read_b128-aligned
#define PSTR 20         // prob q-major [TQ][20]; gather qq*20+lab: uniform qq,
                        // 20 banks + same-lab broadcast -> ~conflict-free

// Gate: sqrt_rn(d2) <= 2.0  <=>  d2 <= 4 + ulp(4)  (bit-exact vs numpy fp32).
#define GATE_D2 0x1.000001p+2f

__global__ __launch_bounds__(256, 8)
void matcher_kernel(const float* __restrict__ logits,
                    const float* __restrict__ pboxes,
                    const int*   __restrict__ tlabels,
                    const float* __restrict__ tboxes,
                    float* __restrict__ out) {
    __shared__ __align__(16) float geo[TQ * GEO_STRIDE];    // 3072 B
    __shared__ float prob[TQ * PSTR];                       // 5120 B -> 8192 total
    const int tid = threadIdx.x;
    const int b   = blockIdx.y;
    const int q0  = blockIdx.x * TQ;

    // ---- staging: wave 0 stages the block's 64 queries (1 q per lane) ----
    if (tid < TQ) {
        const int q = q0 + tid;
        const float* lg = logits + (size_t)(b * QQ + q) * NL;
        float l[NL];
        #pragma unroll
        for (int c = 0; c < NL; ++c) l[c] = lg[c];
        float m = l[0];
        #pragma unroll
        for (int c = 1; c < NL; ++c) m = fmaxf(m, l[c]);
        float e[NL];
        float s = 0.f;
        #pragma unroll
        for (int c = 0; c < NL; ++c) { e[c] = expf(l[c] - m); s += e[c]; }
        const float rs = 1.0f / s;
        #pragma unroll
        for (int c = 0; c < NC; ++c)    // once per block; minor bank aliasing ok
            prob[tid * PSTR + c] = -(e[c] * rs);

        const float* pb = pboxes + (size_t)(b * QQ + q) * 6;
        const float pcx = pb[0], pcy = pb[1], pcz = pb[2];
        const float psx = pb[3], psy = pb[4], psz = pb[5];
        float4* gp = (float4*)(geo + tid * GEO_STRIDE);
        gp[0] = make_float4(pcx, pcy, pcz, psx * psy * psz);
        gp[1] = make_float4(pcx - psx * 0.5f, pcy - psy * 0.5f, pcz - psz * 0.5f, 0.f);
        gp[2] = make_float4(pcx + psx * 0.5f, pcy + psy * 0.5f, pcz + psz * 0.5f, 0.f);
    }

    // ---- per-thread: centers of targets n0..n0+3 ONLY (fast-path state) ----
    const int lane = tid & 63;
    const int w    = tid >> 6;
    const int n0   = lane * 4;
    float tcx[4], tcy[4], tcz[4];
    #pragma unroll
    for (int j = 0; j < 4; ++j) {
        const float* tb = tboxes + (size_t)(b * NN + n0 + j) * 6;
        tcx[j] = tb[0]; tcy[j] = tb[1]; tcz[j] = tb[2];
    }

    __syncthreads();

    const float4 MISS = make_float4(1000000.0f, 1000000.0f, 1000000.0f, 1000000.0f);
    float* ob = out + ((size_t)(b * QQ + q0)) * NN + n0;

    // Wave w owns contiguous rows [w*16, w*16+16). Fast path: one uniform
    // ds_read_b128 + 4 d2 chains + ballot + one coalesced 1-KB row store.
    const int rend = w * 16 + 16;
    #pragma unroll 1
    for (int qq = w * 16; qq < rend; ++qq) {
        const float4* gp = (const float4*)(geo + qq * GEO_STRIDE); // uniform bcast
        const float4 g0 = gp[0];   // pc.xyz, vol1

        // strict fp32, numpy op order, no FMA: feeds the 1e6 discontinuity gate
        float d2v[4];
        int active = 0;
        #pragma unroll
        for (int j = 0; j < 4; ++j) {
            const float dx = __fsub_rn(g0.x, tcx[j]);
            const float dy = __fsub_rn(g0.y, tcy[j]);
            const float dz = __fsub_rn(g0.z, tcz[j]);
            d2v[j] = __fadd_rn(__fadd_rn(__fmul_rn(dx, dx), __fmul_rn(dy, dy)),
                               __fmul_rn(dz, dz));
            active |= (d2v[j] <= GATE_D2);
        }

        float4* orow = (float4*)(ob + (size_t)qq * NN);
        if (!__any(active)) {          // wave-uniform: ~93% of iters
            *orow = MISS;
            continue;
        }

        // ---- slow path (~6.5%): reload target boxes from global (L2-hot)
        // and recompute mn/mx/v2 with the exact R0 expressions (mul by 0.5f
        // is exact scaling -> contraction-proof; v2 is a pure product).
        const float4 g1 = gp[1];       // min1.xyz
        const float4 g2 = gp[2];       // max1.xyz
        float r[4];
        #pragma unroll
        for (int j = 0; j < 4; ++j) {
            const float* tb = tboxes + (size_t)(b * NN + n0 + j) * 6;
            const float cx = tb[0], cy = tb[1], cz = tb[2];
            const float sx = tb[3], sy = tb[4], sz = tb[5];
            const float mnx = cx - sx * 0.5f, mny = cy - sy * 0.5f, mnz = cz - sz * 0.5f;
            const float mxx = cx + sx * 0.5f, mxy = cy + sy * 0.5f, mxz = cz + sz * 0.5f;
            const float v2  = sx * sy * sz;
            const int  lab  = tlabels[b * NN + n0 + j];
            const float negp = prob[qq * PSTR + lab];

            const float dist = __builtin_amdgcn_sqrtf(d2v[j]); // continuous term only

            const float ix = fmaxf(fminf(g2.x, mxx) - fmaxf(g1.x, mnx), 0.f);
            const float iy = fmaxf(fminf(g2.y, mxy) - fmaxf(g1.y, mny), 0.f);
            const float iz = fmaxf(fminf(g2.z, mxz) - fmaxf(g1.z, mnz), 0.f);
            const float iv  = ix * iy * iz;
            const float uni = g0.w + v2 - iv;        // > 0 always (sizes >= 0.5)
            const float iou = iv * __builtin_amdgcn_rcpf(uni);

            const float t = fmaf(5.0f, dist, negp) + fmaf(-2.0f, iou, 2.0f);
            r[j] = (d2v[j] <= GATE_D2) ? t : 1000000.0f;   // bit-exact gate
        }
        *orow = make_float4(r[0], r[1], r[2], r[3]);
    }
}

extern "C" void kernel_launch(void* const* d_in, const int* in_sizes, int n_in,
                              void* d_out, int out_size, void* d_ws, size_t ws_size,
                              hipStream_t stream) {
    const float* logits  = (const float*)d_in[0];  // (B,Q,21)
    const float* pboxes  = (const float*)d_in[1];  // (B,Q,6)
    const int*   tlabels = (const int*)d_in[2];    // (B,N)
    const float* tboxes  = (const float*)d_in[3];  // (B,N,6)
    float* out = (float*)d_out;                    // (B,Q,N) fp32

    dim3 grid(QQ / TQ, BQ);                        // 64 x 64 = 4096 blocks, 8/CU res.
    matcher_kernel<<<grid, dim3(256), 0, stream>>>(logits, pboxes, tlabels, tboxes, out);
}

// Round 9
// 295.305 us; speedup vs baseline: 1.0147x; 1.0147x over previous
//
#include <hip/hip_runtime.h>
#include <math.h>

// B=64, Q=4096, N=256, 20 fg classes + 1 bg. Output (B,Q,N) fp32 = 268 MB.
// KEY SPARSITY FACT: centers uniform in [0,50]^3, gate radius 2.0 ->
// P(dist<=2) ~ 0.027%; P(any of a wave-iter's 256 pairs active) ~ 6.5%.
// 93% of wave-iters take a d2-only fast path and store constant 1e6.
//
// FINAL (R9 = R0 restored). Full ledger of falsified alternatives:
//   R1 split fill + storeless matcher  = 315.5  (stores overlapped, <=20us)
//   R2-R4 softmax-in-slow-path + launch_bounds(256,6) = 314.8 (spills)
//   R5 4-row ILP                       = 297.5  (null: not chain-latency)
//   R6 voxel mask, -84% gate work      = 310.9  (negative: not issue-bound)
//   R7 LDS 32.8->32.0 KB + store bases = 295.7  (null)
//   R8 true 2x occupancy (32 waves/CU) = 299.6  (null: not occupancy)
// Conclusion: timed window = harness poison fill (~175us, 1 GiB @ ~75% peak)
// + restore dispatches + this kernel (~114us, ~45us of which is the
// mandatory 268 MB store at demonstrated fill rate). Structural floor.
#define BQ 64
#define QQ 4096
#define NN 256
#define NC 20
#define NL 21
#define TQ 256          // queries per block
#define GEO_STRIDE 12   // 10 floats used + 2 pad -> 48 B, 16-B aligned (ds_read_b128)
#define PROB_STRIDE 257 // label gather hits distinct banks; staging writes conflict-free

// Gate: sqrt_rn(d2) <= 2.0  <=>  d2 <= 4 + ulp(4)  (bit-exact vs numpy fp32).
#define GATE_D2 0x1.000001p+2f

__global__ __launch_bounds__(256)
void matcher_kernel(const float* __restrict__ logits,
                    const float* __restrict__ pboxes,
                    const int*   __restrict__ tlabels,
                    const float* __restrict__ tboxes,
                    float* __restrict__ out) {
    __shared__ __align__(16) float geo[TQ * GEO_STRIDE];    // 12 KB
    __shared__ float prob[NC * PROB_STRIDE];                // 20.1 KB
    const int tid = threadIdx.x;
    const int b   = blockIdx.y;
    const int q0  = blockIdx.x * TQ;

    // ---- staging: one q per thread (softmax once per q) ----
    {
        const int q = q0 + tid;
        const float* lg = logits + (size_t)(b * QQ + q) * NL;
        float l[NL];
        #pragma unroll
        for (int c = 0; c < NL; ++c) l[c] = lg[c];
        float m = l[0];
        #pragma unroll
        for (int c = 1; c < NL; ++c) m = fmaxf(m, l[c]);
        float e[NL];
        float s = 0.f;
        #pragma unroll
        for (int c = 0; c < NL; ++c) { e[c] = expf(l[c] - m); s += e[c]; }
        const float rs = 1.0f / s;
        #pragma unroll
        for (int c = 0; c < NC; ++c)    // bank (c+tid)%32 -> 2 lanes/bank (free)
            prob[c * PROB_STRIDE + tid] = -(e[c] * rs);

        const float* pb = pboxes + (size_t)(b * QQ + q) * 6;
        const float pcx = pb[0], pcy = pb[1], pcz = pb[2];
        const float psx = pb[3], psy = pb[4], psz = pb[5];
        float4* gp = (float4*)(geo + tid * GEO_STRIDE);
        gp[0] = make_float4(pcx, pcy, pcz, psx * psy * psz);
        gp[1] = make_float4(pcx - psx * 0.5f, pcy - psy * 0.5f, pcz - psz * 0.5f, 0.f);
        gp[2] = make_float4(pcx + psx * 0.5f, pcy + psy * 0.5f, pcz + psz * 0.5f, 0.f);
    }

    // ---- per-thread: quad of targets n0..n0+3 in registers ----
    const int lane = tid & 63;
    const int w    = tid >> 6;
    const int n0   = lane * 4;
    float tcx[4], tcy[4], tcz[4];
    float mn_x[4], mn_y[4], mn_z[4], mx_x[4], mx_y[4], mx_z[4], v2[4];
    int plab[4];
    #pragma unroll
    for (int j = 0; j < 4; ++j) {
        const float* tb = tboxes + (size_t)(b * NN + n0 + j) * 6;
        const float cx = tb[0], cy = tb[1], cz = tb[2];
        const float sx = tb[3], sy = tb[4], sz = tb[5];
        tcx[j] = cx; tcy[j] = cy; tcz[j] = cz;
        mn_x[j] = cx - sx * 0.5f; mn_y[j] = cy - sy * 0.5f; mn_z[j] = cz - sz * 0.5f;
        mx_x[j] = cx + sx * 0.5f; mx_y[j] = cy + sy * 0.5f; mx_z[j] = cz + sz * 0.5f;
        v2[j]   = sx * sy * sz;
        plab[j] = tlabels[b * NN + n0 + j] * PROB_STRIDE;
    }

    __syncthreads();

    const float4 MISS = make_float4(1000000.0f, 1000000.0f, 1000000.0f, 1000000.0f);
    float* ob = out + ((size_t)(b * QQ + q0)) * NN + n0;

    // Each wave handles qq = w, w+4, ... One dwordx4 store per wave-iter
    // covers a contiguous 1-KB q-row (coalesced). Fast path: d2 + gate only.
    for (int qq = w; qq < TQ; qq += 4) {
        const float4* gp = (const float4*)(geo + qq * GEO_STRIDE); // uniform broadcast
        const float4 g0 = gp[0];   // pc.xyz, vol1

        // strict fp32, numpy op order, no FMA: feeds the 1e6 discontinuity gate
        float d2v[4];
        int active = 0;
        #pragma unroll
        for (int j = 0; j < 4; ++j) {
            const float dx = __fsub_rn(g0.x, tcx[j]);
            const float dy = __fsub_rn(g0.y, tcy[j]);
            const float dz = __fsub_rn(g0.z, tcz[j]);
            d2v[j] = __fadd_rn(__fadd_rn(__fmul_rn(dx, dx), __fmul_rn(dy, dy)),
                               __fmul_rn(dz, dz));
            active |= (d2v[j] <= GATE_D2);
        }

        float4* orow = (float4*)(ob + (size_t)qq * NN);
        if (!__any(active)) {          // wave-uniform: ~93% of iters
            *orow = MISS;
            continue;
        }

        const float4 g1 = gp[1];       // min1.xyz
        const float4 g2 = gp[2];       // max1.xyz
        float r[4];
        #pragma unroll
        for (int j = 0; j < 4; ++j) {
            const float negp = prob[plab[j] + qq];

            const float dist = __builtin_amdgcn_sqrtf(d2v[j]); // continuous term only

            const float ix = fmaxf(fminf(g2.x, mx_x[j]) - fmaxf(g1.x, mn_x[j]), 0.f);
            const float iy = fmaxf(fminf(g2.y, mx_y[j]) - fmaxf(g1.y, mn_y[j]), 0.f);
            const float iz = fmaxf(fminf(g2.z, mx_z[j]) - fmaxf(g1.z, mn_z[j]), 0.f);
            const float iv  = ix * iy * iz;
            const float uni = g0.w + v2[j] - iv;     // > 0 always (sizes >= 0.5)
            const float iou = iv * __builtin_amdgcn_rcpf(uni);

            const float t = fmaf(5.0f, dist, negp) + fmaf(-2.0f, iou, 2.0f);
            r[j] = (d2v[j] <= GATE_D2) ? t : 1000000.0f;   // bit-exact gate
        }
        *orow = make_float4(r[0], r[1], r[2], r[3]);
    }
}

extern "C" void kernel_launch(void* const* d_in, const int* in_sizes, int n_in,
                              void* d_out, int out_size, void* d_ws, size_t ws_size,
                              hipStream_t stream) {
    const float* logits  = (const float*)d_in[0];  // (B,Q,21)
    const float* pboxes  = (const float*)d_in[1];  // (B,Q,6)
    const int*   tlabels = (const int*)d_in[2];    // (B,N)
    const float* tboxes  = (const float*)d_in[3];  // (B,N,6)
    float* out = (float*)d_out;                    // (B,Q,N) fp32

    dim3 grid(QQ / TQ, BQ);                        // 16 x 64 = 1024 blocks = 4/CU
    matcher_kernel<<<grid, dim3(256), 0, stream>>>(logits, pboxes, tlabels, tboxes, out);
}